// Round 8
// baseline (280.831 us; speedup 1.0000x reference)
//
#include <hip/hip_runtime.h>
#include <hip/hip_bf16.h>

#define NB 32
#define NN 1024
#define IND 128
#define HD 64

typedef float f32x4 __attribute__((ext_vector_type(4)));
typedef short bf16x8 __attribute__((ext_vector_type(8)));
typedef unsigned short ushortx4 __attribute__((ext_vector_type(4)));

union FragU { unsigned short us[8]; bf16x8 v; };

__device__ __forceinline__ unsigned short f2bf(float f) {
    union { float f; unsigned u; } x; x.f = f;
    unsigned r = x.u + 0x7FFFu + ((x.u >> 16) & 1u);  // RNE
    return (unsigned short)(r >> 16);
}
__device__ __forceinline__ float bf2f(unsigned short h) {
    union { unsigned u; float f; } x; x.u = ((unsigned)h) << 16; return x.f;
}

// async 16B global -> LDS (DMA, no VGPR dest; counted by vmcnt)
__device__ __forceinline__ void gl16(void* lds, const void* g) {
    __builtin_amdgcn_global_load_lds(
        (const __attribute__((address_space(1))) unsigned int*)g,
        (__attribute__((address_space(3))) unsigned int*)lds, 16, 0, 0);
}

// ---------------- kernel 0: weight prep (transpose + hi/lo bf16 split) ------
__global__ void prep_k(const float* __restrict__ W_h, const float* __restrict__ W_fc1,
                       const float* __restrict__ W_g1, const float* __restrict__ W_g2,
                       const float* __restrict__ b_g1, const float* __restrict__ b_g2,
                       unsigned short* __restrict__ WcT_hi, unsigned short* __restrict__ WcT_lo,
                       unsigned short* __restrict__ Wg1T_hi, unsigned short* __restrict__ Wg1T_lo,
                       unsigned short* __restrict__ Wg2T_hi, unsigned short* __restrict__ Wg2T_lo,
                       float* __restrict__ biasP1) {
    int t = blockIdx.x * blockDim.x + threadIdx.x;
    if (t < 16384) {
        int o = t >> 7, k = t & 127;
        float v = (o < 64) ? W_h[k * 64 + o] : W_fc1[k * 64 + (o - 64)];
        unsigned short hi = f2bf(v);
        WcT_hi[t] = hi; WcT_lo[t] = f2bf(v - bf2f(hi));
    } else if (t < 20480) {
        int r = t - 16384; int o = r >> 6, k = r & 63;
        float v = W_g1[k * 64 + o];
        unsigned short hi = f2bf(v);
        Wg1T_hi[r] = hi; Wg1T_lo[r] = f2bf(v - bf2f(hi));
    } else if (t < 24576) {
        int r = t - 20480; int o = r >> 6, k = r & 63;
        float v = W_g2[k * 64 + o];
        unsigned short hi = f2bf(v);
        Wg2T_hi[r] = hi; Wg2T_lo[r] = f2bf(v - bf2f(hi));
    } else if (t < 24640) {
        int j = t - 24576;
        biasP1[j] = b_g1[j] + b_g2[j];
    }
}

// ---------------- kernel 1: h (-> hF frag-major bf16), x_proj (f32), p1 -----
// (unchanged)
__global__ __launch_bounds__(64) void k1(
        const float* __restrict__ x,
        const unsigned short* __restrict__ WcT_hi, const unsigned short* __restrict__ WcT_lo,
        const unsigned short* __restrict__ Wg1T_hi, const unsigned short* __restrict__ Wg1T_lo,
        const float* __restrict__ b_h, const float* __restrict__ b_fc1,
        const float* __restrict__ biasP1,
        unsigned short* __restrict__ hF, float* __restrict__ xproj,
        float* __restrict__ p1) {
    __shared__ unsigned short lds_hi[16 * 64];
    __shared__ unsigned short lds_lo[16 * 64];

    const int lane = threadIdx.x;
    const int lr = lane & 15, lg = lane >> 4;
    const int blk = blockIdx.x;
    const int b = blk >> 6;
    const int n0 = (blk & 63) * 16;

    const float* xp = x + (size_t)(b * NN + n0 + lr) * IND;

    f32x4 xa[4][2];
#pragma unroll
    for (int ks = 0; ks < 4; ks++) {
        const f32x4* ap = (const f32x4*)(xp + 32 * ks + 8 * lg);
        xa[ks][0] = ap[0]; xa[ks][1] = ap[1];
    }

    f32x4 acc[8];
#pragma unroll
    for (int f = 0; f < 8; f++) acc[f] = (f32x4){0.f, 0.f, 0.f, 0.f};

#pragma unroll
    for (int ks = 0; ks < 4; ks++) {
        FragU ah, al;
#pragma unroll
        for (int i = 0; i < 4; i++) {
            unsigned short h0 = f2bf(xa[ks][0][i]); ah.us[i] = h0;     al.us[i]     = f2bf(xa[ks][0][i] - bf2f(h0));
            unsigned short h1 = f2bf(xa[ks][1][i]); ah.us[4 + i] = h1; al.us[4 + i] = f2bf(xa[ks][1][i] - bf2f(h1));
        }
#pragma unroll
        for (int f = 0; f < 8; f++) {
            int off = (16 * f + lr) * 128 + 32 * ks + 8 * lg;
            bf16x8 wh = *(const bf16x8*)(WcT_hi + off);
            bf16x8 wl = *(const bf16x8*)(WcT_lo + off);
            acc[f] = __builtin_amdgcn_mfma_f32_16x16x32_bf16(ah.v, wh, acc[f], 0, 0, 0);
            acc[f] = __builtin_amdgcn_mfma_f32_16x16x32_bf16(ah.v, wl, acc[f], 0, 0, 0);
            acc[f] = __builtin_amdgcn_mfma_f32_16x16x32_bf16(al.v, wh, acc[f], 0, 0, 0);
        }
    }

    const int mb = n0 + 4 * lg;
    const int tile = mb >> 5;
    const int lanepart = lr + 16 * ((mb >> 3) & 3);
    const int j0 = mb & 7;

#pragma unroll
    for (int f = 0; f < 4; f++) {
        int c = 16 * f + lr;
        float bh = b_h[c];
        ushortx4 hv;
#pragma unroll
        for (int r = 0; r < 4; r++) hv[r] = f2bf(acc[f][r] + bh);
        *(ushortx4*)(hF + (size_t)b * 65536 + (size_t)(tile * 4 + f) * 512 + lanepart * 8 + j0) = hv;
    }

#pragma unroll
    for (int f = 4; f < 8; f++) {
        int c = 16 * (f - 4) + lr;
        float bp = b_fc1[c];
#pragma unroll
        for (int r = 0; r < 4; r++) {
            float v = acc[f][r] + bp;
            int n = mb + r;
            xproj[(size_t)(b * NN + n) * 64 + c] = v;
            int ln = 4 * lg + r;
            int idx = ln * 64 + (((c >> 3) ^ (ln & 7)) << 3) + (c & 7);
            unsigned short hi = f2bf(v);
            lds_hi[idx] = hi;
            lds_lo[idx] = f2bf(v - bf2f(hi));
        }
    }
    __syncthreads();

    f32x4 accP[4];
#pragma unroll
    for (int f = 0; f < 4; f++) accP[f] = (f32x4){0.f, 0.f, 0.f, 0.f};
#pragma unroll
    for (int ks = 0; ks < 2; ks++) {
        int c0 = 32 * ks + 8 * lg;
        int idx = lr * 64 + (((c0 >> 3) ^ (lr & 7)) << 3);
        bf16x8 a_hi = *(const bf16x8*)(lds_hi + idx);
        bf16x8 a_lo = *(const bf16x8*)(lds_lo + idx);
#pragma unroll
        for (int f = 0; f < 4; f++) {
            int off = (16 * f + lr) * 64 + c0;
            bf16x8 b_hi = *(const bf16x8*)(Wg1T_hi + off);
            bf16x8 b_lo = *(const bf16x8*)(Wg1T_lo + off);
            accP[f] = __builtin_amdgcn_mfma_f32_16x16x32_bf16(a_hi, b_hi, accP[f], 0, 0, 0);
            accP[f] = __builtin_amdgcn_mfma_f32_16x16x32_bf16(a_hi, b_lo, accP[f], 0, 0, 0);
            accP[f] = __builtin_amdgcn_mfma_f32_16x16x32_bf16(a_lo, b_hi, accP[f], 0, 0, 0);
        }
    }
#pragma unroll
    for (int f = 0; f < 4; f++) {
        int c = 16 * f + lr;
        float bb = biasP1[c];
#pragma unroll
        for (int r = 0; r < 4; r++) {
            int n = mb + r;
            p1[(size_t)(b * NN + n) * 64 + c] = accP[f][r] + bb;
        }
    }
}

// -------- shared k2 main loop: 32 rows x K=1024, BK=256, phase-rotated -----
// phase p: K-tiles visited in order p, p+1, p+2, p+3 (mod 4).
__device__ __forceinline__ void k2_mainloop(
        const float* __restrict__ A, const unsigned short* __restrict__ hF,
        char* smem, int b, int rt, int phase, int w, int lane, f32x4 (&acc)[2]) {
    const int lr = lane & 15, lg = lane >> 4;
    const int wr = w >> 1, wc = w & 1;

    const float* aS[8];
#pragma unroll
    for (int i = 0; i < 8; i++) {
        int rl = w * 8 + i;
        aS[i] = A + (size_t)(b * NN + rt * 32 + rl) * NN + ((lane ^ rl) << 2);
    }
    const unsigned short* hBase = hF + (size_t)b * 65536;

    bf16x8 hb[8][2];

    // prologue: stage tile(phase) -> slot0; load hb(phase)
#pragma unroll
    for (int i = 0; i < 8; i++)
        gl16(smem + (w * 8 + i) * 1024, aS[i] + phase * 256);
#pragma unroll
    for (int ks = 0; ks < 8; ks++)
#pragma unroll
        for (int i = 0; i < 2; i++)
            hb[ks][i] = *(const bf16x8*)(hBase +
                (size_t)((phase * 8 + ks) * 4 + 2 * wc + i) * 512 + lane * 8);
    __syncthreads();

    const int rl_c = 16 * wr + lr;

#define COMPUTE(ks, Abase)                                                     \
    {                                                                          \
        int g0 = (ks) * 8 + lg * 2;                                            \
        f32x4 a0 = *(const f32x4*)((Abase) + ((g0 ^ rl_c) << 4));              \
        f32x4 a1 = *(const f32x4*)((Abase) + (((g0 + 1) ^ rl_c) << 4));        \
        FragU au;                                                              \
        _Pragma("unroll")                                                      \
        for (int ii = 0; ii < 4; ii++) {                                       \
            au.us[ii] = f2bf(a0[ii]); au.us[4 + ii] = f2bf(a1[ii]);            \
        }                                                                      \
        acc[0] = __builtin_amdgcn_mfma_f32_16x16x32_bf16(au.v, hb[ks][0], acc[0], 0, 0, 0); \
        acc[1] = __builtin_amdgcn_mfma_f32_16x16x32_bf16(au.v, hb[ks][1], acc[1], 0, 0, 0); \
    }

#pragma unroll
    for (int tt = 0; tt < 4; tt++) {
        const int slot = tt & 1;
        const int tn = (phase + tt + 1) & 3;   // next K-tile
        const char* Abase = smem + slot * 32768 + rl_c * 1024;

        if (tt < 3) {
#pragma unroll
            for (int i = 0; i < 8; i++)
                gl16(smem + (slot ^ 1) * 32768 + (w * 8 + i) * 1024,
                     aS[i] + tn * 256);
        }

        COMPUTE(0, Abase) COMPUTE(1, Abase) COMPUTE(2, Abase) COMPUTE(3, Abase)
        if (tt < 3) {
#pragma unroll
            for (int ks = 0; ks < 4; ks++)
#pragma unroll
                for (int i = 0; i < 2; i++)
                    hb[ks][i] = *(const bf16x8*)(hBase +
                        (size_t)((tn * 8 + ks) * 4 + 2 * wc + i) * 512 + lane * 8);
        }
        COMPUTE(4, Abase) COMPUTE(5, Abase) COMPUTE(6, Abase) COMPUTE(7, Abase)
        if (tt < 3) {
#pragma unroll
            for (int ks = 4; ks < 8; ks++)
#pragma unroll
                for (int i = 0; i < 2; i++)
                    hb[ks][i] = *(const bf16x8*)(hBase +
                        (size_t)((tn * 8 + ks) * 4 + 2 * wc + i) * 512 + lane * 8);
        }
        __syncthreads();
    }
#undef COMPUTE
}

// ---------------- kernel 2: x_new = A@h (phase-rotated); fused epilogue -----
__global__ __launch_bounds__(256, 2) void k2(
        const float* __restrict__ A, const unsigned short* __restrict__ hF,
        const unsigned short* __restrict__ Wg2T_hi, const unsigned short* __restrict__ Wg2T_lo,
        const float* __restrict__ p1, const float* __restrict__ xproj,
        float* __restrict__ out) {
    __shared__ char smem[65536];

    const int tid = threadIdx.x;
    const int w = tid >> 6, lane = tid & 63;
    const int lr = lane & 15, lg = lane >> 4;
    const int wr = w >> 1, wc = w & 1;

    const int wgid = ((int)blockIdx.x & 7) * 128 + ((int)blockIdx.x >> 3);
    const int b = wgid >> 5;
    const int rt = wgid & 31;

    f32x4 acc[2];
    acc[0] = (f32x4){0.f, 0.f, 0.f, 0.f};
    acc[1] = (f32x4){0.f, 0.f, 0.f, 0.f};

    k2_mainloop(A, hF, smem, b, rt, wgid & 3, w, lane, acc);

    // ---- epilogue ----
    unsigned short* th = (unsigned short*)(smem + wr * 4096);
    unsigned short* tl = th + 1024;
#pragma unroll
    for (int i = 0; i < 2; i++) {
        int c = 32 * wc + 16 * i + lr;
#pragma unroll
        for (int r = 0; r < 4; r++) {
            int ln = 4 * lg + r;
            int idx = ln * 64 + (((c >> 3) ^ (ln & 7)) << 3) + (c & 7);
            float v = acc[i][r];
            unsigned short hi = f2bf(v);
            th[idx] = hi;
            tl[idx] = f2bf(v - bf2f(hi));
        }
    }
    __syncthreads();

    f32x4 accG[2];
    accG[0] = (f32x4){0.f, 0.f, 0.f, 0.f};
    accG[1] = (f32x4){0.f, 0.f, 0.f, 0.f};
#pragma unroll
    for (int ksk = 0; ksk < 2; ksk++) {
        int c0k = 32 * ksk + 8 * lg;
        int idx = lr * 64 + (((c0k >> 3) ^ (lr & 7)) << 3);
        bf16x8 a_hi = *(const bf16x8*)(th + idx);
        bf16x8 a_lo = *(const bf16x8*)(tl + idx);
#pragma unroll
        for (int i = 0; i < 2; i++) {
            int off = (16 * (2 * wc + i) + lr) * 64 + c0k;
            bf16x8 b_hi = *(const bf16x8*)(Wg2T_hi + off);
            bf16x8 b_lo = *(const bf16x8*)(Wg2T_lo + off);
            accG[i] = __builtin_amdgcn_mfma_f32_16x16x32_bf16(a_hi, b_hi, accG[i], 0, 0, 0);
            accG[i] = __builtin_amdgcn_mfma_f32_16x16x32_bf16(a_hi, b_lo, accG[i], 0, 0, 0);
            accG[i] = __builtin_amdgcn_mfma_f32_16x16x32_bf16(a_lo, b_hi, accG[i], 0, 0, 0);
        }
    }

#pragma unroll
    for (int i = 0; i < 2; i++) {
        int c = 16 * (2 * wc + i) + lr;
#pragma unroll
        for (int r = 0; r < 4; r++) {
            int n = rt * 32 + 16 * wr + 4 * lg + r;
            size_t g = (size_t)(b * NN + n) * 64 + c;
            float z = p1[g] + accG[i][r];
            float gate = 1.f / (1.f + __expf(-z));
            float xpv = xproj[g];
            out[g] = acc[i][r] * gate + xpv * (1.f - gate);
        }
    }
}

// ---------------- probes: main loop x4 passes, rotated strips ---------------
// Each pass reads a DIFFERENT row-strip (L2 evicted between) -> L3-resident
// steady state, matching the real kernel. ROT toggles K-phase rotation.
template <int ROT>
__global__ __launch_bounds__(256, 2) void k2mp(
        const float* __restrict__ A, const unsigned short* __restrict__ hF,
        float* __restrict__ sink) {
    __shared__ char smem[65536];

    const int tid = threadIdx.x;
    const int w = tid >> 6, lane = tid & 63;

    const int wgid = ((int)blockIdx.x & 7) * 128 + ((int)blockIdx.x >> 3);
    const int b = wgid >> 5;
    const int rt = wgid & 31;

    f32x4 acc[2];
    acc[0] = (f32x4){0.f, 0.f, 0.f, 0.f};
    acc[1] = (f32x4){0.f, 0.f, 0.f, 0.f};

    for (int p = 0; p < 4; p++) {
        int strip = (rt + p * 8) & 31;
        int ph = ROT ? ((wgid + p) & 3) : 0;
        k2_mainloop(A, hF, smem, b, strip, ph, w, lane, acc);
    }

    float* sp = sink + ((size_t)blockIdx.x * 256 + tid) * 8;
    *(f32x4*)(sp) = acc[0];
    *(f32x4*)(sp + 4) = acc[1];
}

extern "C" void kernel_launch(void* const* d_in, const int* in_sizes, int n_in,
                              void* d_out, int out_size, void* d_ws, size_t ws_size,
                              hipStream_t stream) {
    const float* x     = (const float*)d_in[0];
    const float* A     = (const float*)d_in[1];
    const float* W_h   = (const float*)d_in[2];
    const float* b_h   = (const float*)d_in[3];
    const float* W_fc1 = (const float*)d_in[4];
    const float* b_fc1 = (const float*)d_in[5];
    const float* W_g1  = (const float*)d_in[6];
    const float* b_g1  = (const float*)d_in[7];
    const float* W_g2  = (const float*)d_in[8];
    const float* b_g2  = (const float*)d_in[9];
    float* out = (float*)d_out;

    char* ws = (char*)d_ws;
    unsigned short* WcT_hi  = (unsigned short*)(ws);            // 32 KB
    unsigned short* WcT_lo  = (unsigned short*)(ws + 32768);    // 32 KB
    unsigned short* Wg1T_hi = (unsigned short*)(ws + 65536);    // 8 KB
    unsigned short* Wg1T_lo = (unsigned short*)(ws + 73728);    // 8 KB
    unsigned short* Wg2T_hi = (unsigned short*)(ws + 81920);    // 8 KB
    unsigned short* Wg2T_lo = (unsigned short*)(ws + 90112);    // 8 KB
    float*          bP1     = (float*)(ws + 98304);             // 256 B
    unsigned short* hF      = (unsigned short*)(ws + 131072);                      // 4 MB
    float*          xprj    = (float*)(ws + 131072 + 4194304);                     // 8 MB
    float*          p1      = (float*)(ws + 131072 + 4194304 + 8388608);           // 8 MB
    float*          sinkR   = (float*)(ws + (size_t)32 * 1024 * 1024);             // 8 MB
    float*          sinkN   = (float*)(ws + (size_t)42 * 1024 * 1024);             // 8 MB

    prep_k<<<97, 256, 0, stream>>>(W_h, W_fc1, W_g1, W_g2, b_g1, b_g2,
                                   WcT_hi, WcT_lo, Wg1T_hi, Wg1T_lo, Wg2T_hi, Wg2T_lo, bP1);
    k1<<<2048, 64, 0, stream>>>(x, WcT_hi, WcT_lo, Wg1T_hi, Wg1T_lo, b_h, b_fc1, bP1,
                                hF, xprj, p1);
    k2<<<1024, 256, 0, stream>>>(A, hF, Wg2T_hi, Wg2T_lo, p1, xprj, out);

    // diagnostics: within-run A/B on K-phase rotation (scratch sinks only)
    k2mp<1><<<1024, 256, 0, stream>>>(A, hF, sinkR);
    k2mp<0><<<1024, 256, 0, stream>>>(A, hF, sinkN);
}

// Round 9
// 103.918 us; speedup vs baseline: 2.7024x; 2.7024x over previous
//
#include <hip/hip_runtime.h>
#include <hip/hip_bf16.h>

#define NB 32
#define NN 1024
#define IND 128
#define HD 64

typedef float f32x4 __attribute__((ext_vector_type(4)));
typedef short bf16x8 __attribute__((ext_vector_type(8)));
typedef unsigned short ushortx4 __attribute__((ext_vector_type(4)));

union FragU { unsigned short us[8]; bf16x8 v; };

__device__ __forceinline__ unsigned short f2bf(float f) {
    union { float f; unsigned u; } x; x.f = f;
    unsigned r = x.u + 0x7FFFu + ((x.u >> 16) & 1u);  // RNE
    return (unsigned short)(r >> 16);
}
__device__ __forceinline__ float bf2f(unsigned short h) {
    union { unsigned u; float f; } x; x.u = ((unsigned)h) << 16; return x.f;
}

// ---------------- kernel 0: weight prep (transpose + hi/lo bf16 split) ------
__global__ void prep_k(const float* __restrict__ W_h, const float* __restrict__ W_fc1,
                       const float* __restrict__ W_g1, const float* __restrict__ W_g2,
                       const float* __restrict__ b_g1, const float* __restrict__ b_g2,
                       unsigned short* __restrict__ WcT_hi, unsigned short* __restrict__ WcT_lo,
                       unsigned short* __restrict__ Wg1T_hi, unsigned short* __restrict__ Wg1T_lo,
                       unsigned short* __restrict__ Wg2T_hi, unsigned short* __restrict__ Wg2T_lo,
                       float* __restrict__ biasP1) {
    int t = blockIdx.x * blockDim.x + threadIdx.x;
    if (t < 16384) {
        int o = t >> 7, k = t & 127;
        float v = (o < 64) ? W_h[k * 64 + o] : W_fc1[k * 64 + (o - 64)];
        unsigned short hi = f2bf(v);
        WcT_hi[t] = hi; WcT_lo[t] = f2bf(v - bf2f(hi));
    } else if (t < 20480) {
        int r = t - 16384; int o = r >> 6, k = r & 63;
        float v = W_g1[k * 64 + o];
        unsigned short hi = f2bf(v);
        Wg1T_hi[r] = hi; Wg1T_lo[r] = f2bf(v - bf2f(hi));
    } else if (t < 24576) {
        int r = t - 20480; int o = r >> 6, k = r & 63;
        float v = W_g2[k * 64 + o];
        unsigned short hi = f2bf(v);
        Wg2T_hi[r] = hi; Wg2T_lo[r] = f2bf(v - bf2f(hi));
    } else if (t < 24640) {
        int j = t - 24576;
        biasP1[j] = b_g1[j] + b_g2[j];
    }
}

// ---------------- kernel 1: h (-> hF frag-major bf16), x_proj (f32), p1 -----
// (unchanged)
__global__ __launch_bounds__(64) void k1(
        const float* __restrict__ x,
        const unsigned short* __restrict__ WcT_hi, const unsigned short* __restrict__ WcT_lo,
        const unsigned short* __restrict__ Wg1T_hi, const unsigned short* __restrict__ Wg1T_lo,
        const float* __restrict__ b_h, const float* __restrict__ b_fc1,
        const float* __restrict__ biasP1,
        unsigned short* __restrict__ hF, float* __restrict__ xproj,
        float* __restrict__ p1) {
    __shared__ unsigned short lds_hi[16 * 64];
    __shared__ unsigned short lds_lo[16 * 64];

    const int lane = threadIdx.x;
    const int lr = lane & 15, lg = lane >> 4;
    const int blk = blockIdx.x;
    const int b = blk >> 6;
    const int n0 = (blk & 63) * 16;

    const float* xp = x + (size_t)(b * NN + n0 + lr) * IND;

    f32x4 xa[4][2];
#pragma unroll
    for (int ks = 0; ks < 4; ks++) {
        const f32x4* ap = (const f32x4*)(xp + 32 * ks + 8 * lg);
        xa[ks][0] = ap[0]; xa[ks][1] = ap[1];
    }

    f32x4 acc[8];
#pragma unroll
    for (int f = 0; f < 8; f++) acc[f] = (f32x4){0.f, 0.f, 0.f, 0.f};

#pragma unroll
    for (int ks = 0; ks < 4; ks++) {
        FragU ah, al;
#pragma unroll
        for (int i = 0; i < 4; i++) {
            unsigned short h0 = f2bf(xa[ks][0][i]); ah.us[i] = h0;     al.us[i]     = f2bf(xa[ks][0][i] - bf2f(h0));
            unsigned short h1 = f2bf(xa[ks][1][i]); ah.us[4 + i] = h1; al.us[4 + i] = f2bf(xa[ks][1][i] - bf2f(h1));
        }
#pragma unroll
        for (int f = 0; f < 8; f++) {
            int off = (16 * f + lr) * 128 + 32 * ks + 8 * lg;
            bf16x8 wh = *(const bf16x8*)(WcT_hi + off);
            bf16x8 wl = *(const bf16x8*)(WcT_lo + off);
            acc[f] = __builtin_amdgcn_mfma_f32_16x16x32_bf16(ah.v, wh, acc[f], 0, 0, 0);
            acc[f] = __builtin_amdgcn_mfma_f32_16x16x32_bf16(ah.v, wl, acc[f], 0, 0, 0);
            acc[f] = __builtin_amdgcn_mfma_f32_16x16x32_bf16(al.v, wh, acc[f], 0, 0, 0);
        }
    }

    const int mb = n0 + 4 * lg;
    const int tile = mb >> 5;
    const int lanepart = lr + 16 * ((mb >> 3) & 3);
    const int j0 = mb & 7;

#pragma unroll
    for (int f = 0; f < 4; f++) {
        int c = 16 * f + lr;
        float bh = b_h[c];
        ushortx4 hv;
#pragma unroll
        for (int r = 0; r < 4; r++) hv[r] = f2bf(acc[f][r] + bh);
        *(ushortx4*)(hF + (size_t)b * 65536 + (size_t)(tile * 4 + f) * 512 + lanepart * 8 + j0) = hv;
    }

#pragma unroll
    for (int f = 4; f < 8; f++) {
        int c = 16 * (f - 4) + lr;
        float bp = b_fc1[c];
#pragma unroll
        for (int r = 0; r < 4; r++) {
            float v = acc[f][r] + bp;
            int n = mb + r;
            xproj[(size_t)(b * NN + n) * 64 + c] = v;
            int ln = 4 * lg + r;
            int idx = ln * 64 + (((c >> 3) ^ (ln & 7)) << 3) + (c & 7);
            unsigned short hi = f2bf(v);
            lds_hi[idx] = hi;
            lds_lo[idx] = f2bf(v - bf2f(hi));
        }
    }
    __syncthreads();

    f32x4 accP[4];
#pragma unroll
    for (int f = 0; f < 4; f++) accP[f] = (f32x4){0.f, 0.f, 0.f, 0.f};
#pragma unroll
    for (int ks = 0; ks < 2; ks++) {
        int c0 = 32 * ks + 8 * lg;
        int idx = lr * 64 + (((c0 >> 3) ^ (lr & 7)) << 3);
        bf16x8 a_hi = *(const bf16x8*)(lds_hi + idx);
        bf16x8 a_lo = *(const bf16x8*)(lds_lo + idx);
#pragma unroll
        for (int f = 0; f < 4; f++) {
            int off = (16 * f + lr) * 64 + c0;
            bf16x8 b_hi = *(const bf16x8*)(Wg1T_hi + off);
            bf16x8 b_lo = *(const bf16x8*)(Wg1T_lo + off);
            accP[f] = __builtin_amdgcn_mfma_f32_16x16x32_bf16(a_hi, b_hi, accP[f], 0, 0, 0);
            accP[f] = __builtin_amdgcn_mfma_f32_16x16x32_bf16(a_hi, b_lo, accP[f], 0, 0, 0);
            accP[f] = __builtin_amdgcn_mfma_f32_16x16x32_bf16(a_lo, b_hi, accP[f], 0, 0, 0);
        }
    }
#pragma unroll
    for (int f = 0; f < 4; f++) {
        int c = 16 * f + lr;
        float bb = biasP1[c];
#pragma unroll
        for (int r = 0; r < 4; r++) {
            int n = mb + r;
            p1[(size_t)(b * NN + n) * 64 + c] = accP[f][r] + bb;
        }
    }
}

// ---------------- kernel 2: x_new = A@h, reg-direct TLP; fused epilogue -----
// grid 2048 x 256 (8 blocks/CU -> 32 waves/CU). Block = one 16-row strip of
// one batch; wave w owns output cols 16w..16w+15 (one 16x16 frag, full K).
// NO LDS staging: A-frag loaded straight to regs (wave-load = 16 rows x
// 128 B contiguous), hF frag = 1 KB contiguous (L2). 2-deep static pipeline;
// latency hidden by 32-wave TLP. A-frag is identical across the 4 waves of a
// block (frag depends on rows+k only) -> dup loads served by L1.
__global__ __launch_bounds__(256, 8) void k2(
        const float* __restrict__ A, const unsigned short* __restrict__ hF,
        const unsigned short* __restrict__ Wg2T_hi, const unsigned short* __restrict__ Wg2T_lo,
        const float* __restrict__ p1, const float* __restrict__ xproj,
        float* __restrict__ out) {
    __shared__ unsigned short th[16 * 64];
    __shared__ unsigned short tl[16 * 64];

    const int tid = threadIdx.x;
    const int w = tid >> 6, lane = tid & 63;
    const int lr = lane & 15, lg = lane >> 4;

    // XCD-bijective swizzle (2048 % 8 == 0)
    const int bid = blockIdx.x;
    const int wgid = (bid & 7) * 256 + (bid >> 3);
    const int b = wgid >> 6;
    const int strip = wgid & 63;

    const float* Arow = A + (size_t)(b * NN + strip * 16 + lr) * NN + 8 * lg;
    const unsigned short* hp = hF + (size_t)b * 65536 + w * 512 + lane * 8;

    f32x4 acc = (f32x4){0.f, 0.f, 0.f, 0.f};

    // 2-deep static pipeline (indices compile-time via full unroll)
    f32x4 a0[2], a1[2];
    bf16x8 hb[2];
    a0[0] = *(const f32x4*)(Arow);
    a1[0] = *(const f32x4*)(Arow + 4);
    hb[0] = *(const bf16x8*)(hp);

#pragma unroll
    for (int ks = 0; ks < 32; ks++) {
        const int cur = ks & 1, nxt = cur ^ 1;
        if (ks < 31) {
            a0[nxt] = *(const f32x4*)(Arow + 32 * (ks + 1));
            a1[nxt] = *(const f32x4*)(Arow + 32 * (ks + 1) + 4);
            hb[nxt] = *(const bf16x8*)(hp + (size_t)(ks + 1) * 2048);
        }
        FragU au;
#pragma unroll
        for (int i = 0; i < 4; i++) {
            au.us[i] = f2bf(a0[cur][i]);
            au.us[4 + i] = f2bf(a1[cur][i]);
        }
        acc = __builtin_amdgcn_mfma_f32_16x16x32_bf16(au.v, hb[cur], acc, 0, 0, 0);
    }

    // ---- epilogue (round-3-verified structure): block tile 16 rows x 64 cols
    {
        int c = 16 * w + lr;
#pragma unroll
        for (int r = 0; r < 4; r++) {
            int row = 4 * lg + r;
            int idx = row * 64 + (((c >> 3) ^ (row & 7)) << 3) + (c & 7);
            float v = acc[r];
            unsigned short hi = f2bf(v);
            th[idx] = hi;
            tl[idx] = f2bf(v - bf2f(hi));
        }
    }
    __syncthreads();

    // g2 = x_new @ W_g2 (split precision); wave w computes col-frag f=w
    f32x4 accG = (f32x4){0.f, 0.f, 0.f, 0.f};
#pragma unroll
    for (int ksk = 0; ksk < 2; ksk++) {
        int c0k = 32 * ksk + 8 * lg;
        int idx = lr * 64 + (((c0k >> 3) ^ (lr & 7)) << 3);
        bf16x8 a_hi = *(const bf16x8*)(th + idx);
        bf16x8 a_lo = *(const bf16x8*)(tl + idx);
        int off = (16 * w + lr) * 64 + c0k;
        bf16x8 b_hi = *(const bf16x8*)(Wg2T_hi + off);
        bf16x8 b_lo = *(const bf16x8*)(Wg2T_lo + off);
        accG = __builtin_amdgcn_mfma_f32_16x16x32_bf16(a_hi, b_hi, accG, 0, 0, 0);
        accG = __builtin_amdgcn_mfma_f32_16x16x32_bf16(a_hi, b_lo, accG, 0, 0, 0);
        accG = __builtin_amdgcn_mfma_f32_16x16x32_bf16(a_lo, b_hi, accG, 0, 0, 0);
    }

    // fused epilogue: gate = sigmoid(p1 + g2); out = xnew*g + xproj*(1-g)
    {
        int c = 16 * w + lr;
#pragma unroll
        for (int r = 0; r < 4; r++) {
            int n = strip * 16 + 4 * lg + r;
            size_t g = (size_t)(b * NN + n) * 64 + c;
            float z = p1[g] + accG[r];
            float gate = 1.f / (1.f + __expf(-z));
            float xpv = xproj[g];
            out[g] = acc[r] * gate + xpv * (1.f - gate);
        }
    }
}

extern "C" void kernel_launch(void* const* d_in, const int* in_sizes, int n_in,
                              void* d_out, int out_size, void* d_ws, size_t ws_size,
                              hipStream_t stream) {
    const float* x     = (const float*)d_in[0];
    const float* A     = (const float*)d_in[1];
    const float* W_h   = (const float*)d_in[2];
    const float* b_h   = (const float*)d_in[3];
    const float* W_fc1 = (const float*)d_in[4];
    const float* b_fc1 = (const float*)d_in[5];
    const float* W_g1  = (const float*)d_in[6];
    const float* b_g1  = (const float*)d_in[7];
    const float* W_g2  = (const float*)d_in[8];
    const float* b_g2  = (const float*)d_in[9];
    float* out = (float*)d_out;

    char* ws = (char*)d_ws;
    unsigned short* WcT_hi  = (unsigned short*)(ws);            // 32 KB
    unsigned short* WcT_lo  = (unsigned short*)(ws + 32768);    // 32 KB
    unsigned short* Wg1T_hi = (unsigned short*)(ws + 65536);    // 8 KB
    unsigned short* Wg1T_lo = (unsigned short*)(ws + 73728);    // 8 KB
    unsigned short* Wg2T_hi = (unsigned short*)(ws + 81920);    // 8 KB
    unsigned short* Wg2T_lo = (unsigned short*)(ws + 90112);    // 8 KB
    float*          bP1     = (float*)(ws + 98304);             // 256 B
    unsigned short* hF      = (unsigned short*)(ws + 131072);                      // 4 MB
    float*          xprj    = (float*)(ws + 131072 + 4194304);                     // 8 MB
    float*          p1      = (float*)(ws + 131072 + 4194304 + 8388608);           // 8 MB

    prep_k<<<97, 256, 0, stream>>>(W_h, W_fc1, W_g1, W_g2, b_g1, b_g2,
                                   WcT_hi, WcT_lo, Wg1T_hi, Wg1T_lo, Wg2T_hi, Wg2T_lo, bP1);
    k1<<<2048, 64, 0, stream>>>(x, WcT_hi, WcT_lo, Wg1T_hi, Wg1T_lo, b_h, b_fc1, bP1,
                                hF, xprj, p1);
    k2<<<2048, 256, 0, stream>>>(A, hF, Wg2T_hi, Wg2T_lo, p1, xprj, out);
}

// Round 10
// 63.257 us; speedup vs baseline: 4.4395x; 1.6428x over previous
//
#include <hip/hip_runtime.h>
#include <hip/hip_bf16.h>

#define NB 32
#define NN 1024
#define IND 128
#define HD 64

typedef float f32x4 __attribute__((ext_vector_type(4)));
typedef short bf16x8 __attribute__((ext_vector_type(8)));
typedef unsigned short ushortx4 __attribute__((ext_vector_type(4)));

union FragU { unsigned short us[8]; bf16x8 v; };

__device__ __forceinline__ unsigned short f2bf(float f) {
    union { float f; unsigned u; } x; x.f = f;
    unsigned r = x.u + 0x7FFFu + ((x.u >> 16) & 1u);  // RNE
    return (unsigned short)(r >> 16);
}
__device__ __forceinline__ float bf2f(unsigned short h) {
    union { unsigned u; float f; } x; x.u = ((unsigned)h) << 16; return x.f;
}

// async 16B global -> LDS (DMA, no VGPR dest; counted by vmcnt)
__device__ __forceinline__ void gl16(void* lds, const void* g) {
    __builtin_amdgcn_global_load_lds(
        (const __attribute__((address_space(1))) unsigned int*)g,
        (__attribute__((address_space(3))) unsigned int*)lds, 16, 0, 0);
}

// ---------------- kernel 0: weight prep (transpose + hi/lo bf16 split) ------
__global__ void prep_k(const float* __restrict__ W_h, const float* __restrict__ W_fc1,
                       const float* __restrict__ W_g1, const float* __restrict__ W_g2,
                       const float* __restrict__ b_g1, const float* __restrict__ b_g2,
                       unsigned short* __restrict__ WcT_hi, unsigned short* __restrict__ WcT_lo,
                       unsigned short* __restrict__ Wg1T_hi, unsigned short* __restrict__ Wg1T_lo,
                       unsigned short* __restrict__ Wg2T_hi, unsigned short* __restrict__ Wg2T_lo,
                       float* __restrict__ biasP1) {
    int t = blockIdx.x * blockDim.x + threadIdx.x;
    if (t < 16384) {
        int o = t >> 7, k = t & 127;
        float v = (o < 64) ? W_h[k * 64 + o] : W_fc1[k * 64 + (o - 64)];
        unsigned short hi = f2bf(v);
        WcT_hi[t] = hi; WcT_lo[t] = f2bf(v - bf2f(hi));
    } else if (t < 20480) {
        int r = t - 16384; int o = r >> 6, k = r & 63;
        float v = W_g1[k * 64 + o];
        unsigned short hi = f2bf(v);
        Wg1T_hi[r] = hi; Wg1T_lo[r] = f2bf(v - bf2f(hi));
    } else if (t < 24576) {
        int r = t - 20480; int o = r >> 6, k = r & 63;
        float v = W_g2[k * 64 + o];
        unsigned short hi = f2bf(v);
        Wg2T_hi[r] = hi; Wg2T_lo[r] = f2bf(v - bf2f(hi));
    } else if (t < 24640) {
        int j = t - 24576;
        biasP1[j] = b_g1[j] + b_g2[j];
    }
}

// ---------------- kernel 1: h (-> hF frag-major bf16), x_proj (f32), p1 -----
// (unchanged)
__global__ __launch_bounds__(64) void k1(
        const float* __restrict__ x,
        const unsigned short* __restrict__ WcT_hi, const unsigned short* __restrict__ WcT_lo,
        const unsigned short* __restrict__ Wg1T_hi, const unsigned short* __restrict__ Wg1T_lo,
        const float* __restrict__ b_h, const float* __restrict__ b_fc1,
        const float* __restrict__ biasP1,
        unsigned short* __restrict__ hF, float* __restrict__ xproj,
        float* __restrict__ p1) {
    __shared__ unsigned short lds_hi[16 * 64];
    __shared__ unsigned short lds_lo[16 * 64];

    const int lane = threadIdx.x;
    const int lr = lane & 15, lg = lane >> 4;
    const int blk = blockIdx.x;
    const int b = blk >> 6;
    const int n0 = (blk & 63) * 16;

    const float* xp = x + (size_t)(b * NN + n0 + lr) * IND;

    f32x4 xa[4][2];
#pragma unroll
    for (int ks = 0; ks < 4; ks++) {
        const f32x4* ap = (const f32x4*)(xp + 32 * ks + 8 * lg);
        xa[ks][0] = ap[0]; xa[ks][1] = ap[1];
    }

    f32x4 acc[8];
#pragma unroll
    for (int f = 0; f < 8; f++) acc[f] = (f32x4){0.f, 0.f, 0.f, 0.f};

#pragma unroll
    for (int ks = 0; ks < 4; ks++) {
        FragU ah, al;
#pragma unroll
        for (int i = 0; i < 4; i++) {
            unsigned short h0 = f2bf(xa[ks][0][i]); ah.us[i] = h0;     al.us[i]     = f2bf(xa[ks][0][i] - bf2f(h0));
            unsigned short h1 = f2bf(xa[ks][1][i]); ah.us[4 + i] = h1; al.us[4 + i] = f2bf(xa[ks][1][i] - bf2f(h1));
        }
#pragma unroll
        for (int f = 0; f < 8; f++) {
            int off = (16 * f + lr) * 128 + 32 * ks + 8 * lg;
            bf16x8 wh = *(const bf16x8*)(WcT_hi + off);
            bf16x8 wl = *(const bf16x8*)(WcT_lo + off);
            acc[f] = __builtin_amdgcn_mfma_f32_16x16x32_bf16(ah.v, wh, acc[f], 0, 0, 0);
            acc[f] = __builtin_amdgcn_mfma_f32_16x16x32_bf16(ah.v, wl, acc[f], 0, 0, 0);
            acc[f] = __builtin_amdgcn_mfma_f32_16x16x32_bf16(al.v, wh, acc[f], 0, 0, 0);
        }
    }

    const int mb = n0 + 4 * lg;
    const int tile = mb >> 5;
    const int lanepart = lr + 16 * ((mb >> 3) & 3);
    const int j0 = mb & 7;

#pragma unroll
    for (int f = 0; f < 4; f++) {
        int c = 16 * f + lr;
        float bh = b_h[c];
        ushortx4 hv;
#pragma unroll
        for (int r = 0; r < 4; r++) hv[r] = f2bf(acc[f][r] + bh);
        *(ushortx4*)(hF + (size_t)b * 65536 + (size_t)(tile * 4 + f) * 512 + lanepart * 8 + j0) = hv;
    }

#pragma unroll
    for (int f = 4; f < 8; f++) {
        int c = 16 * (f - 4) + lr;
        float bp = b_fc1[c];
#pragma unroll
        for (int r = 0; r < 4; r++) {
            float v = acc[f][r] + bp;
            int n = mb + r;
            xproj[(size_t)(b * NN + n) * 64 + c] = v;
            int ln = 4 * lg + r;
            int idx = ln * 64 + (((c >> 3) ^ (ln & 7)) << 3) + (c & 7);
            unsigned short hi = f2bf(v);
            lds_hi[idx] = hi;
            lds_lo[idx] = f2bf(v - bf2f(hi));
        }
    }
    __syncthreads();

    f32x4 accP[4];
#pragma unroll
    for (int f = 0; f < 4; f++) accP[f] = (f32x4){0.f, 0.f, 0.f, 0.f};
#pragma unroll
    for (int ks = 0; ks < 2; ks++) {
        int c0 = 32 * ks + 8 * lg;
        int idx = lr * 64 + (((c0 >> 3) ^ (lr & 7)) << 3);
        bf16x8 a_hi = *(const bf16x8*)(lds_hi + idx);
        bf16x8 a_lo = *(const bf16x8*)(lds_lo + idx);
#pragma unroll
        for (int f = 0; f < 4; f++) {
            int off = (16 * f + lr) * 64 + c0;
            bf16x8 b_hi = *(const bf16x8*)(Wg1T_hi + off);
            bf16x8 b_lo = *(const bf16x8*)(Wg1T_lo + off);
            accP[f] = __builtin_amdgcn_mfma_f32_16x16x32_bf16(a_hi, b_hi, accP[f], 0, 0, 0);
            accP[f] = __builtin_amdgcn_mfma_f32_16x16x32_bf16(a_hi, b_lo, accP[f], 0, 0, 0);
            accP[f] = __builtin_amdgcn_mfma_f32_16x16x32_bf16(a_lo, b_hi, accP[f], 0, 0, 0);
        }
    }
#pragma unroll
    for (int f = 0; f < 4; f++) {
        int c = 16 * f + lr;
        float bb = biasP1[c];
#pragma unroll
        for (int r = 0; r < 4; r++) {
            int n = mb + r;
            p1[(size_t)(b * NN + n) * 64 + c] = accP[f][r] + bb;
        }
    }
}

// ---------------- kernel 2: x_new = A@h, staged DMA, 4 blocks/CU ------------
// grid 2048 x 256, __launch_bounds__(256,4) -> 4 blocks/CU, 16 waves/CU,
// 2x the per-CU DMA streams of round 7. Block = 16 rows x 64 cols, BK=256,
// double-buffered 2 x 16 KB A-slots. Wave w = col-frag w (cols 16w..16w+15),
// all 4 waves share the LDS A-frags (broadcast reads). A staged with
// pre-swizzled source (granule ^ row), read with same XOR. hF frags are
// 1 KB contiguous L2 loads into regs (reloaded in place per tile).
__global__ __launch_bounds__(256, 4) void k2(
        const float* __restrict__ A, const unsigned short* __restrict__ hF,
        const unsigned short* __restrict__ Wg2T_hi, const unsigned short* __restrict__ Wg2T_lo,
        const float* __restrict__ p1, const float* __restrict__ xproj,
        float* __restrict__ out) {
    __shared__ char smem[32768];   // A: 2 slots x 16 KB

    const int tid = threadIdx.x;
    const int w = tid >> 6, lane = tid & 63;
    const int lr = lane & 15, lg = lane >> 4;

    // XCD-bijective swizzle (2048 % 8 == 0)
    const int bid = blockIdx.x;
    const int wgid = (bid & 7) * 256 + (bid >> 3);
    const int b = wgid >> 6;
    const int strip = wgid & 63;

    // staging sources: wave w stages rows 4w..4w+3 (1 KB each, pre-swizzled)
    const float* aS[4];
#pragma unroll
    for (int i = 0; i < 4; i++) {
        int rl = w * 4 + i;
        aS[i] = A + (size_t)(b * NN + strip * 16 + rl) * NN + ((lane ^ rl) << 2);
    }
    const unsigned short* hp = hF + (size_t)b * 65536 + w * 512 + lane * 8;

    f32x4 acc = (f32x4){0.f, 0.f, 0.f, 0.f};
    bf16x8 hb[8];

    // prologue: stage A-tile 0 -> slot 0; load hb for tile 0
#pragma unroll
    for (int i = 0; i < 4; i++)
        gl16(smem + (w * 4 + i) * 1024, aS[i]);
#pragma unroll
    for (int ks = 0; ks < 8; ks++)
        hb[ks] = *(const bf16x8*)(hp + (size_t)ks * 2048);
    __syncthreads();

#define COMPUTE(ks, Abase)                                                     \
    {                                                                          \
        int g0 = (ks) * 8 + lg * 2;                                            \
        f32x4 a0 = *(const f32x4*)((Abase) + ((g0 ^ lr) << 4));                \
        f32x4 a1 = *(const f32x4*)((Abase) + (((g0 + 1) ^ lr) << 4));          \
        FragU au;                                                              \
        _Pragma("unroll")                                                      \
        for (int ii = 0; ii < 4; ii++) {                                       \
            au.us[ii] = f2bf(a0[ii]); au.us[4 + ii] = f2bf(a1[ii]);            \
        }                                                                      \
        acc = __builtin_amdgcn_mfma_f32_16x16x32_bf16(au.v, hb[ks], acc, 0, 0, 0); \
    }

#pragma unroll
    for (int t = 0; t < 4; t++) {
        const int slot = t & 1;
        const char* Abase = smem + slot * 16384 + lr * 1024;

        // stage next A-tile into the other slot (hides under this tile's MFMAs)
        if (t < 3) {
#pragma unroll
            for (int i = 0; i < 4; i++)
                gl16(smem + (slot ^ 1) * 16384 + (w * 4 + i) * 1024,
                     aS[i] + (t + 1) * 256);
        }

        COMPUTE(0, Abase) COMPUTE(1, Abase) COMPUTE(2, Abase) COMPUTE(3, Abase)
        if (t < 3) {   // reload hb[0..3] for next tile (just consumed)
#pragma unroll
            for (int ks = 0; ks < 4; ks++)
                hb[ks] = *(const bf16x8*)(hp + (size_t)((t + 1) * 8 + ks) * 2048);
        }
        COMPUTE(4, Abase) COMPUTE(5, Abase) COMPUTE(6, Abase) COMPUTE(7, Abase)
        if (t < 3) {   // reload hb[4..7]
#pragma unroll
            for (int ks = 4; ks < 8; ks++)
                hb[ks] = *(const bf16x8*)(hp + (size_t)((t + 1) * 8 + ks) * 2048);
        }
        __syncthreads();   // drains this tile's DMA + hb loads
    }
#undef COMPUTE

    // ---- epilogue (r9-verified 16x64 form), reusing smem ----
    unsigned short* th = (unsigned short*)smem;
    unsigned short* tl = th + 1024;
    {
        int c = 16 * w + lr;
#pragma unroll
        for (int r = 0; r < 4; r++) {
            int row = 4 * lg + r;
            int idx = row * 64 + (((c >> 3) ^ (row & 7)) << 3) + (c & 7);
            float v = acc[r];
            unsigned short hi = f2bf(v);
            th[idx] = hi;
            tl[idx] = f2bf(v - bf2f(hi));
        }
    }
    __syncthreads();

    // g2 = x_new @ W_g2 (split precision); wave w computes col-frag f=w
    f32x4 accG = (f32x4){0.f, 0.f, 0.f, 0.f};
#pragma unroll
    for (int ksk = 0; ksk < 2; ksk++) {
        int c0k = 32 * ksk + 8 * lg;
        int idx = lr * 64 + (((c0k >> 3) ^ (lr & 7)) << 3);
        bf16x8 a_hi = *(const bf16x8*)(th + idx);
        bf16x8 a_lo = *(const bf16x8*)(tl + idx);
        int off = (16 * w + lr) * 64 + c0k;
        bf16x8 b_hi = *(const bf16x8*)(Wg2T_hi + off);
        bf16x8 b_lo = *(const bf16x8*)(Wg2T_lo + off);
        accG = __builtin_amdgcn_mfma_f32_16x16x32_bf16(a_hi, b_hi, accG, 0, 0, 0);
        accG = __builtin_amdgcn_mfma_f32_16x16x32_bf16(a_hi, b_lo, accG, 0, 0, 0);
        accG = __builtin_amdgcn_mfma_f32_16x16x32_bf16(a_lo, b_hi, accG, 0, 0, 0);
    }

    // fused epilogue: gate = sigmoid(p1 + g2); out = xnew*g + xproj*(1-g)
    {
        int c = 16 * w + lr;
#pragma unroll
        for (int r = 0; r < 4; r++) {
            int n = strip * 16 + 4 * lg + r;
            size_t g = (size_t)(b * NN + n) * 64 + c;
            float z = p1[g] + accG[r];
            float gate = 1.f / (1.f + __expf(-z));
            float xpv = xproj[g];
            out[g] = acc[r] * gate + xpv * (1.f - gate);
        }
    }
}

extern "C" void kernel_launch(void* const* d_in, const int* in_sizes, int n_in,
                              void* d_out, int out_size, void* d_ws, size_t ws_size,
                              hipStream_t stream) {
    const float* x     = (const float*)d_in[0];
    const float* A     = (const float*)d_in[1];
    const float* W_h   = (const float*)d_in[2];
    const float* b_h   = (const float*)d_in[3];
    const float* W_fc1 = (const float*)d_in[4];
    const float* b_fc1 = (const float*)d_in[5];
    const float* W_g1  = (const float*)d_in[6];
    const float* b_g1  = (const float*)d_in[7];
    const float* W_g2  = (const float*)d_in[8];
    const float* b_g2  = (const float*)d_in[9];
    float* out = (float*)d_out;

    char* ws = (char*)d_ws;
    unsigned short* WcT_hi  = (unsigned short*)(ws);            // 32 KB
    unsigned short* WcT_lo  = (unsigned short*)(ws + 32768);    // 32 KB
    unsigned short* Wg1T_hi = (unsigned short*)(ws + 65536);    // 8 KB
    unsigned short* Wg1T_lo = (unsigned short*)(ws + 73728);    // 8 KB
    unsigned short* Wg2T_hi = (unsigned short*)(ws + 81920);    // 8 KB
    unsigned short* Wg2T_lo = (unsigned short*)(ws + 90112);    // 8 KB
    float*          bP1     = (float*)(ws + 98304);             // 256 B
    unsigned short* hF      = (unsigned short*)(ws + 131072);                      // 4 MB
    float*          xprj    = (float*)(ws + 131072 + 4194304);                     // 8 MB
    float*          p1      = (float*)(ws + 131072 + 4194304 + 8388608);           // 8 MB

    prep_k<<<97, 256, 0, stream>>>(W_h, W_fc1, W_g1, W_g2, b_g1, b_g2,
                                   WcT_hi, WcT_lo, Wg1T_hi, Wg1T_lo, Wg2T_hi, Wg2T_lo, bP1);
    k1<<<2048, 64, 0, stream>>>(x, WcT_hi, WcT_lo, Wg1T_hi, Wg1T_lo, b_h, b_fc1, bP1,
                                hF, xprj, p1);
    k2<<<2048, 256, 0, stream>>>(A, hF, Wg2T_hi, Wg2T_lo, p1, xprj, out);
}